// Round 11
// baseline (4685.309 us; speedup 1.0000x reference)
//
#include <hip/hip_runtime.h>
#include <hip/hip_fp16.h>
#include <stdint.h>

#define Bsz 64
#define Tsz 1024
#define Dsz 256
#define UNITSn 256
#define Zdim 1024      // 4*UNITS

typedef _Float16 f16x8  __attribute__((ext_vector_type(8)));
typedef float    f32x4  __attribute__((ext_vector_type(4)));
typedef uint32_t u32x4  __attribute__((ext_vector_type(4)));

#define MFMA16(D, A, B) D = __builtin_amdgcn_mfma_f32_16x16x32_f16( \
    __builtin_bit_cast(f16x8, A), __builtin_bit_cast(f16x8, B), D, 0, 0, 0)

__device__ __forceinline__ float sigm(float x)   { return 1.0f / (1.0f + __expf(-x)); }
__device__ __forceinline__ float tanh_f(float x) { return 1.0f - 2.0f / (__expf(2.0f * x) + 1.0f); }

// U[256][1024] fp32 -> UT[1024][256] f16 (transposed, k-contiguous)
__global__ __launch_bounds__(256) void convert_u(const float* __restrict__ U,
                                                 _Float16* __restrict__ UT) {
  int i = blockIdx.x * 256 + threadIdx.x;   // 262144
  int n = i >> 8, k = i & 255;
  UT[i] = (_Float16)U[(size_t)k * Zdim + n];
}

// W[256][1024] fp32 -> MFMA B-fragments for lstm v11 (layout identical to R10,
// numerically verified). Fragment f = ks*8 + nt (ks=0..7, nt=g*2+sub), thread
// t = w*64+l: lane holds W[k=ks*32+(l>>4)*8+j][col=g*256+w*32+sub*16+(l&15)].
// Channels: ks0..3 -> Wres (AGPR, 32 frags); ks5 -> Wl (LDS, 8);
//           ks4 -> Ws m0..7, ks6 -> Ws m8..15, ks7 -> Ws m16..23 (stream, 24).
__global__ __launch_bounds__(256) void convert_w11(const float* __restrict__ W,
                                                   uint4* __restrict__ Wres,
                                                   uint4* __restrict__ Wl,
                                                   uint4* __restrict__ Ws) {
  int i = blockIdx.x * 256 + threadIdx.x;   // 64*512 = 32768 uint4
  if (i >= 32768) return;
  int f = i >> 9, t = i & 511;
  int w = t >> 6, l = t & 63;
  int ks = f >> 3, nt = f & 7;
  int g = nt >> 1, sub = nt & 1;
  int col = g * 256 + w * 32 + sub * 16 + (l & 15);
  int kb = ks * 32 + ((l >> 4) << 3);
  uint32_t d[4];
#pragma unroll
  for (int e = 0; e < 4; e++) {
    int k = kb + 2 * e;
    float w0 = W[(size_t)k * Zdim + col];
    float w1 = W[(size_t)(k + 1) * Zdim + col];
    __half2 p = __floats2half2_rn(w0, w1);
    d[e] = __builtin_bit_cast(uint32_t, p);
  }
  uint4 v = make_uint4(d[0], d[1], d[2], d[3]);
  if (ks < 4)       Wres[f * 512 + t] = v;                  // f 0..31
  else if (ks == 4) Ws[(nt) * 512 + t] = v;                 // m 0..7
  else if (ks == 5) Wl[nt * 512 + t] = v;                   // LDS
  else if (ks == 6) Ws[(8 + nt) * 512 + t] = v;             // m 8..15
  else              Ws[(16 + nt) * 512 + t] = v;            // m 16..23
}

// xz[(tloc*64+b)*1024+n] = x[b][t][:] @ U[:,n] + bias[n] via f16 MFMA. (verified)
__global__ __launch_bounds__(256) void proj_mfma(
    const float* __restrict__ x, const _Float16* __restrict__ UT,
    const float* __restrict__ bias, float* __restrict__ xz, int t0) {
  __shared__ _Float16 Ax[64][40];
  __shared__ _Float16 Ux[256][40];
  const int tid  = threadIdx.x;
  const int w    = tid >> 6, lane = tid & 63;
  const int lr   = lane & 15, kg = lane >> 4;
  const int n0   = blockIdx.x * 256;
  const int tloc = blockIdx.y;
  const int t    = t0 + tloc;
  const int arow = tid >> 2, ak = (tid & 3) * 8;

  f32x4 acc[4][4];
#pragma unroll
  for (int mi = 0; mi < 4; mi++)
#pragma unroll
    for (int ni = 0; ni < 4; ni++) acc[mi][ni] = f32x4{0.f, 0.f, 0.f, 0.f};

  for (int k0 = 0; k0 < Dsz; k0 += 32) {
    const float* xp = x + ((size_t)arow * Tsz + t) * Dsz + k0 + ak;
    float4 p0 = *(const float4*)xp;
    float4 p1 = *(const float4*)(xp + 4);
    const _Float16* up = UT + (size_t)(n0 + tid) * Dsz + k0;
    f16x8 u0 = *(const f16x8*)up;
    f16x8 u1 = *(const f16x8*)(up + 8);
    f16x8 u2 = *(const f16x8*)(up + 16);
    f16x8 u3 = *(const f16x8*)(up + 24);
    __syncthreads();
    f16x8 a8;
    a8[0] = (_Float16)p0.x; a8[1] = (_Float16)p0.y;
    a8[2] = (_Float16)p0.z; a8[3] = (_Float16)p0.w;
    a8[4] = (_Float16)p1.x; a8[5] = (_Float16)p1.y;
    a8[6] = (_Float16)p1.z; a8[7] = (_Float16)p1.w;
    *(f16x8*)&Ax[arow][ak] = a8;
    *(f16x8*)&Ux[tid][0]  = u0;
    *(f16x8*)&Ux[tid][8]  = u1;
    *(f16x8*)&Ux[tid][16] = u2;
    *(f16x8*)&Ux[tid][24] = u3;
    __syncthreads();
    f16x8 af[4], uf[4];
#pragma unroll
    for (int mi = 0; mi < 4; mi++) af[mi] = *(const f16x8*)&Ax[mi * 16 + lr][kg * 8];
#pragma unroll
    for (int ni = 0; ni < 4; ni++) uf[ni] = *(const f16x8*)&Ux[w * 64 + ni * 16 + lr][kg * 8];
#pragma unroll
    for (int mi = 0; mi < 4; mi++)
#pragma unroll
      for (int ni = 0; ni < 4; ni++)
        acc[mi][ni] = __builtin_amdgcn_mfma_f32_16x16x32_f16(af[mi], uf[ni],
                                                             acc[mi][ni], 0, 0, 0);
  }
#pragma unroll
  for (int ni = 0; ni < 4; ni++) {
    int col = n0 + w * 64 + ni * 16 + lr;
    float bs = bias[col];
#pragma unroll
    for (int mi = 0; mi < 4; mi++) {
      f32x4 v = acc[mi][ni];
#pragma unroll
      for (int r = 0; r < 4; r++) {
        int brow = mi * 16 + kg * 4 + r;
        xz[((size_t)tloc * 64 + brow) * Zdim + col] = v[r] + bs;
      }
    }
  }
}

// One WG (512 thr = 8 waves) per batch (64 WGs -> 1 WG/CU by grid size).
// Wave w owns units w*32..+31, all 4 gates. Per step 64 MFMA/wave; A = h
// broadcast. W frags: 32 pinned in AGPRs ("+a", remat-proof, MFMA reads
// natively) + 8 LDS + 24 L2-stream (192 KB/step, staggered 4-frag batches).
__global__ __launch_bounds__(512) void lstm_chunk(
    const float* __restrict__ xz, const uint4* __restrict__ WresB,
    const uint4* __restrict__ WlB, const uint4* __restrict__ Ws,
    float* __restrict__ out, uint4* __restrict__ h_state,
    float* __restrict__ c_state, int t0, int Tc, int n_out) {
  __shared__ uint4 Wl[8 * 512];     // 64 KB (ks5 frags)
  __shared__ uint4 hq[2][32];       // 1 KB packed-f16 h, double-buffered

  const int tid = threadIdx.x;
  const int b   = blockIdx.x;
  const int w   = tid >> 6, l = tid & 63;
  const int kg  = l >> 4, l31 = l & 31;
  const int sub = kg & 1;

  // AGPR-pinned W fragments (ks 0..3): 128 AGPRs/thread
  u32x4 wa[32];
#pragma unroll
  for (int s = 0; s < 32; s++)
    wa[s] = __builtin_bit_cast(u32x4, WresB[(size_t)s * 512 + tid]);
#pragma unroll
  for (int s = 0; s < 32; s++)
    asm volatile("" : "+a"(wa[s]));
  // LDS W fragments (ks 5)
#pragma unroll
  for (int s = 0; s < 8; s++) Wl[s * 512 + tid] = WlB[(size_t)s * 512 + tid];

  float c = 0.0f;
  if (t0 == 0) {
    if (tid < 64) ((uint4*)hq)[tid] = make_uint4(0, 0, 0, 0);
  } else {
    if (tid < 32) ((uint4*)hq)[tid] = h_state[(size_t)b * 32 + tid];
    c = c_state[(size_t)b * 256 + w * 32 + l31];
  }
  __syncthreads();

  const float* xzb = xz + (size_t)b * Zdim + w * 32 + l31;
  float nx0 = xzb[0], nx1 = xzb[256], nx2 = xzb[512], nx3 = xzb[768];
  const uint4* wsp = Ws + tid;

  for (int tl = 0; tl < Tc; tl++) {
    const int buf = tl & 1;
    const uint4* hb4 = hq[buf];
    uint4 hA[8];
#pragma unroll
    for (int ks = 0; ks < 8; ks++) hA[ks] = hb4[ks * 4 + kg];

    // pass-A streams: ks4 nt0-3 (m0-3), ks6 nt0-3 (m8-11)
    uint4 s40 = wsp[0 * 512], s41 = wsp[1 * 512], s42 = wsp[2 * 512], s43 = wsp[3 * 512];
    uint4 s60 = wsp[8 * 512], s61 = wsp[9 * 512], s62 = wsp[10 * 512], s63 = wsp[11 * 512];

    // ---- pass A: n-tiles 0..3 (gates 0,1) ----
    f32x4 D0 = {0.f, 0.f, 0.f, 0.f}, D1 = D0, D2 = D0, D3 = D0;
#pragma unroll
    for (int ks = 0; ks < 4; ks++) {
      uint4 A = hA[ks];
      MFMA16(D0, A, wa[ks * 8 + 0]); MFMA16(D1, A, wa[ks * 8 + 1]);
      MFMA16(D2, A, wa[ks * 8 + 2]); MFMA16(D3, A, wa[ks * 8 + 3]);
    }
    uint4 s70 = wsp[16 * 512], s71 = wsp[17 * 512], s72 = wsp[18 * 512], s73 = wsp[19 * 512];
    { uint4 A = hA[4];
      MFMA16(D0, A, s40); MFMA16(D1, A, s41); MFMA16(D2, A, s42); MFMA16(D3, A, s43); }
    uint4 t40 = wsp[4 * 512], t41 = wsp[5 * 512], t42 = wsp[6 * 512], t43 = wsp[7 * 512];
    { uint4 A = hA[5];
      uint4 b0 = Wl[0 * 512 + tid], b1 = Wl[1 * 512 + tid];
      uint4 b2 = Wl[2 * 512 + tid], b3 = Wl[3 * 512 + tid];
      MFMA16(D0, A, b0); MFMA16(D1, A, b1); MFMA16(D2, A, b2); MFMA16(D3, A, b3); }
    uint4 t60 = wsp[12 * 512], t61 = wsp[13 * 512], t62 = wsp[14 * 512], t63 = wsp[15 * 512];
    { uint4 A = hA[6];
      MFMA16(D0, A, s60); MFMA16(D1, A, s61); MFMA16(D2, A, s62); MFMA16(D3, A, s63); }
    uint4 t70 = wsp[20 * 512], t71 = wsp[21 * 512], t72 = wsp[22 * 512], t73 = wsp[23 * 512];
    { uint4 A = hA[7];
      MFMA16(D0, A, s70); MFMA16(D1, A, s71); MFMA16(D2, A, s72); MFMA16(D3, A, s73); }
    float z0 = sub ? D1[0] : D0[0];   // gate 0 (i)
    float z1 = sub ? D3[0] : D2[0];   // gate 1 (f)

    // ---- pass B: n-tiles 4..7 (gates 2,3) ----
    f32x4 E0 = {0.f, 0.f, 0.f, 0.f}, E1 = E0, E2 = E0, E3 = E0;
#pragma unroll
    for (int ks = 0; ks < 4; ks++) {
      uint4 A = hA[ks];
      MFMA16(E0, A, wa[ks * 8 + 4]); MFMA16(E1, A, wa[ks * 8 + 5]);
      MFMA16(E2, A, wa[ks * 8 + 6]); MFMA16(E3, A, wa[ks * 8 + 7]);
    }
    { uint4 A = hA[4];
      MFMA16(E0, A, t40); MFMA16(E1, A, t41); MFMA16(E2, A, t42); MFMA16(E3, A, t43); }
    { uint4 A = hA[5];
      uint4 b0 = Wl[4 * 512 + tid], b1 = Wl[5 * 512 + tid];
      uint4 b2 = Wl[6 * 512 + tid], b3 = Wl[7 * 512 + tid];
      MFMA16(E0, A, b0); MFMA16(E1, A, b1); MFMA16(E2, A, b2); MFMA16(E3, A, b3); }
    { uint4 A = hA[6];
      MFMA16(E0, A, t60); MFMA16(E1, A, t61); MFMA16(E2, A, t62); MFMA16(E3, A, t63); }
    { uint4 A = hA[7];
      MFMA16(E0, A, t70); MFMA16(E1, A, t71); MFMA16(E2, A, t72); MFMA16(E3, A, t73); }
    float z2 = sub ? E1[0] : E0[0];   // gate 2 (g)
    float z3 = sub ? E3[0] : E2[0];   // gate 3 (o)

    // ---- gates (all lanes; lanes 32..63 duplicate 0..31) ----
    z0 += nx0; z1 += nx1; z2 += nx2; z3 += nx3;
    if (tl + 1 < Tc) {
      const float* xn = xzb + (size_t)(tl + 1) * (Bsz * Zdim);
      nx0 = xn[0]; nx1 = xn[256]; nx2 = xn[512]; nx3 = xn[768];
    }
    float ig = sigm(z0), fg = sigm(z1), gg = tanh_f(z2), og = sigm(z3);
    c = fg * c + ig * gg;
    float hn = og * tanh_f(c);
    if (l < 32) {
      int ot = (t0 + tl) - (Tsz - n_out);
      if (ot >= 0) out[((size_t)b * n_out + ot) * UNITSn + w * 32 + l] = hn;
      ((_Float16*)hq[buf ^ 1])[w * 32 + l] = (_Float16)hn;
    }
    __syncthreads();
  }
  if (tid < 32) h_state[(size_t)b * 32 + tid] = ((uint4*)hq)[(Tc & 1) * 32 + tid];
  if (l < 32) c_state[(size_t)b * 256 + w * 32 + l] = c;
}

extern "C" void kernel_launch(void* const* d_in, const int* in_sizes, int n_in,
                              void* d_out, int out_size, void* d_ws, size_t ws_size,
                              hipStream_t stream) {
  const float* x    = (const float*)d_in[0];
  const float* U    = (const float*)d_in[1];
  const float* W    = (const float*)d_in[2];
  const float* bias = (const float*)d_in[3];
  float* out = (float*)d_out;
  const int n_out = out_size / (Bsz * UNITSn);   // 32

  uint8_t* ws = (uint8_t*)d_ws;
  uint4* Wres     = (uint4*)ws;                    // 256 KB (f 0..31)
  uint4* Wl       = (uint4*)(ws + (256u << 10));   //  64 KB (ks5)
  uint4* Ws_      = (uint4*)(ws + (320u << 10));   // 192 KB (m 0..23)
  _Float16* UT    = (_Float16*)(ws + (512u << 10));// 512 KB
  uint4* h_state  = (uint4*)(ws + (1024u << 10));  //  32 KB
  float* c_state  = (float*)(ws + (1056u << 10));  //  64 KB
  float* xz       = (float*)(ws + (2u << 20));     // Tc*64*1024 fp32

  int Tc = Tsz;
  while (Tc > 1 && (size_t)(2u << 20) + (size_t)Tc * (Bsz * Zdim) * 4 > ws_size) Tc >>= 1;

  convert_w11<<<dim3(128), dim3(256), 0, stream>>>(W, Wres, Wl, Ws_);
  convert_u<<<dim3(1024), dim3(256), 0, stream>>>(U, UT);

  for (int t0 = 0; t0 < Tsz; t0 += Tc) {
    proj_mfma<<<dim3(4, Tc), dim3(256), 0, stream>>>(x, UT, bias, xz, t0);
    lstm_chunk<<<dim3(Bsz), dim3(512), 0, stream>>>(xz, Wres, Wl, Ws_,
                                                    out, h_state, c_state,
                                                    t0, Tc, n_out);
  }
}